// Round 7
// baseline (856.282 us; speedup 1.0000x reference)
//
#include <hip/hip_runtime.h>
#include <hip/hip_bf16.h>

// Viterbi CRF decode: B=512, T=512, K=64.
// Round 9: TWO independent batch recurrences interleaved per wave.
// Evidence: r5-r8 (scalar-LDS/wide-LDS x readlane/bpermute) all land at
// 400-412us, VALUBusy 38% -- broadcast mechanism and tc read path are
// falsified as bottlenecks. Remaining model: total time = serial per-batch
// recurrence latency (all batches already concurrent; SIMDs mostly idle),
// per-step cost = VALU issue at single-wave cadence + dependency/waitcnt
// bubbles that no other wave fills. Fix that wins under both readings:
// interleave batch 2p and 2p+1 in one wave. B's independent ops fill A's
// bubbles; tc quads (ds_read_b128 ring) are shared -- loaded once per pair.
// Per-batch semantics untouched: bpermute broadcast (uniform idx), FP
// association (s+tc)+e exact, 8 ascending strict-> chains of 8 merged
// low-group-first => jnp.argmax first-index tie-break. Bitwise-identical.
// Grid: 256 blocks x 64 thr (1 wave handles 2 batches). Backtrace
// unchanged (verified), still 512 blocks.
// Workspace: hist uint8 [B][512][K] = 16.78 MB (row 511 pad) + best_last[B].

#define TT 512
#define BB 512
#define KK 64
#define RS 68   // padded row stride (floats) for transposed trans in LDS

#define NEG_INF (-3.402823466e38f)

__global__ __launch_bounds__(64, 1) void viterbi_fwd(
    const float* __restrict__ emissions,   // [B,T,K]
    const int* __restrict__ attn_mask,     // [B,T]
    const float* __restrict__ start_t,     // [K]
    const float* __restrict__ end_t,       // [K]
    const float* __restrict__ trans,       // [K,K]
    unsigned char* __restrict__ hist,      // [B,512,K] (row 511 pad)
    int* __restrict__ best_last)           // [B]
{
    const int bp = blockIdx.x;            // batch pair
    const int bA = 2 * bp, bB = 2 * bp + 1;
    const int j = threadIdx.x & 63;

    // transposed + padded transitions: ldsT[j*RS + i] = trans[i][j]
    __shared__ __align__(16) float ldsT[KK * RS];   // 17408 B
    __shared__ float sv[KK];

#pragma unroll 4
    for (int i = 0; i < KK; ++i)
        ldsT[j * RS + i] = trans[i * KK + j];
    __syncthreads();

    const float* row = &ldsT[j * RS];

    const float* ebA = emissions + (size_t)bA * TT * KK;
    const float* ebB = emissions + (size_t)bB * TT * KK;
    const int*   mbA = attn_mask + (size_t)bA * TT;
    const int*   mbB = attn_mask + (size_t)bB * TT;
    unsigned char* hbA = hist + (size_t)bA * TT * KK;
    unsigned char* hbB = hist + (size_t)bB * TT * KK;

    // lane j holds score[j] for both batches
    float sA = start_t[j] + ebA[j];
    float sB = start_t[j] + ebB[j];

    // 2-deep prefetch rings per batch
    float e0A = ebA[KK + j], e1A = ebA[2 * KK + j];
    float e0B = ebB[KK + j], e1B = ebB[2 * KK + j];
    int   m0A = mbA[1], m1A = mbA[2];
    int   m0B = mbB[1], m1B = mbB[2];

    for (int t = 1; t < TT; ++t) {
        float eA = e0A; e0A = e1A;
        float eB = e0B; e0B = e1B;
        int   mA_ = m0A; m0A = m1A;
        int   mB_ = m0B; m0B = m1B;
        int tn = (t + 2 < TT) ? (t + 2) : (TT - 1);
        e1A = ebA[(size_t)tn * KK + j];
        e1B = ebB[(size_t)tn * KK + j];
        m1A = mbA[tn];
        m1B = mbB[tn];

        // opaque zero offset: loop-variant address -> no LICM of ds reads,
        // provenance (addrspace 3) kept -> ds_read_b128 + imm offsets.
        unsigned off = 0;
        asm volatile("" : "+v"(off));
        const float* rb = row + off;

#define LDQ(q) (*(const float4*)(rb + 4 * (q)))
#define BCA(i) __uint_as_float(__builtin_amdgcn_ds_bpermute(4 * (i), __float_as_uint(sA)))
#define BCB(i) __uint_as_float(__builtin_amdgcn_ds_bpermute(4 * (i), __float_as_uint(sB)))

        float gvA[8]; int giA[8];
        float gvB[8]; int giB[8];

        // tc quad ring shared by both batches
        float4 qa0 = LDQ(0), qa1 = LDQ(1), qb0 = LDQ(2), qb1 = LDQ(3);
#pragma unroll
        for (int g = 0; g < 8; ++g) {
            float4 p0 = qa0, p1 = qa1;            // dead unless g<6
            if (g < 6) { p0 = LDQ(2 * g + 4); p1 = LDQ(2 * g + 5); }

            const int base = 8 * g;
            float c;
            // 8 candidates each, ascending strict-> chains (first-index
            // ties); A and B interleaved -> independent work fills bubbles
            float bvA = (BCA(base + 0) + qa0.x) + eA; int iA = base;
            float bvB = (BCB(base + 0) + qa0.x) + eB; int iB = base;
            c = (BCA(base + 1) + qa0.y) + eA; if (c > bvA) { bvA = c; iA = base + 1; }
            c = (BCB(base + 1) + qa0.y) + eB; if (c > bvB) { bvB = c; iB = base + 1; }
            c = (BCA(base + 2) + qa0.z) + eA; if (c > bvA) { bvA = c; iA = base + 2; }
            c = (BCB(base + 2) + qa0.z) + eB; if (c > bvB) { bvB = c; iB = base + 2; }
            c = (BCA(base + 3) + qa0.w) + eA; if (c > bvA) { bvA = c; iA = base + 3; }
            c = (BCB(base + 3) + qa0.w) + eB; if (c > bvB) { bvB = c; iB = base + 3; }
            c = (BCA(base + 4) + qa1.x) + eA; if (c > bvA) { bvA = c; iA = base + 4; }
            c = (BCB(base + 4) + qa1.x) + eB; if (c > bvB) { bvB = c; iB = base + 4; }
            c = (BCA(base + 5) + qa1.y) + eA; if (c > bvA) { bvA = c; iA = base + 5; }
            c = (BCB(base + 5) + qa1.y) + eB; if (c > bvB) { bvB = c; iB = base + 5; }
            c = (BCA(base + 6) + qa1.z) + eA; if (c > bvA) { bvA = c; iA = base + 6; }
            c = (BCB(base + 6) + qa1.z) + eB; if (c > bvB) { bvB = c; iB = base + 6; }
            c = (BCA(base + 7) + qa1.w) + eA; if (c > bvA) { bvA = c; iA = base + 7; }
            c = (BCB(base + 7) + qa1.w) + eB; if (c > bvB) { bvB = c; iB = base + 7; }
            gvA[g] = bvA; giA[g] = iA;
            gvB[g] = bvB; giB[g] = iB;

            qa0 = qb0; qa1 = qb1; qb0 = p0; qb1 = p1;
        }

        // merge group winners ascending (first-index tie rule preserved)
        float bestA = gvA[0]; int wiA = giA[0];
        float bestB = gvB[0]; int wiB = giB[0];
#pragma unroll
        for (int g = 1; g < 8; ++g) {
            if (gvA[g] > bestA) { bestA = gvA[g]; wiA = giA[g]; }
            if (gvB[g] > bestB) { bestB = gvB[g]; wiB = giB[g]; }
        }

#undef LDQ
#undef BCA
#undef BCB

        hbA[(size_t)(t - 1) * KK + j] = (unsigned char)wiA;
        hbB[(size_t)(t - 1) * KK + j] = (unsigned char)wiB;
        sA = mA_ ? bestA : sA;
        sB = mB_ ? bestB : sB;
    }

    // final: add end transitions, argmax over tags (first-index ties)
    float finA = sA + end_t[j];
    sv[j] = finA;
    __syncthreads();
    if (j == 0) {
        float bv = sv[0]; int bt = 0;
#pragma unroll
        for (int k = 1; k < KK; ++k) {
            float v = sv[k];
            if (v > bv) { bv = v; bt = k; }
        }
        best_last[bA] = bt;
    }
    __syncthreads();
    float finB = sB + end_t[j];
    sv[j] = finB;
    __syncthreads();
    if (j == 0) {
        float bv = sv[0]; int bt = 0;
#pragma unroll
        for (int k = 1; k < KK; ++k) {
            float v = sv[k];
            if (v > bv) { bv = v; bt = k; }
        }
        best_last[bB] = bt;
    }
}

__global__ __launch_bounds__(64) void viterbi_bt(
    const unsigned char* __restrict__ hist,  // [B,512,K]
    const int* __restrict__ attn_mask,       // [B,T]
    const int* __restrict__ best_last,       // [B]
    int* __restrict__ out)                   // [B,T] int32
{
    const int b = blockIdx.x;
    const int l = threadIdx.x;
    __shared__ int path[TT];

    const unsigned int* hw = (const unsigned int*)(hist + (size_t)b * TT * KK);
    const int* mb = attn_mask + (size_t)b * TT;

    int tag = best_last[b];          // broadcast (uniform on all lanes)
    if (l == 0) path[TT - 1] = tag;

    unsigned int dwA[16], dwB[16];
    int mA, mB;

    auto loadChunk = [&](int c, unsigned int (&dw)[16], int& mreg) {
#pragma unroll
        for (int q4 = 0; q4 < 16; ++q4)
            dw[q4] = hw[c * 1024 + q4 * 64 + l];   // 4 rows per wave-load
        int midx = c * 64 + l + 1;
        if (midx > TT - 1) midx = TT - 1;
        mreg = mb[midx];                            // lane l: mask[b][c*64+l+1]
    };
    auto procChunk = [&](int c, unsigned int (&dw)[16], int mreg) {
#pragma unroll
        for (int q = 63; q >= 0; --q) {
            int r = c * 64 + q;
            if (r < TT - 1) {
                // byte hist[r][tag]: local dword q*16+(tag>>2)
                unsigned int d = __shfl(dw[q >> 2], ((q & 3) << 4) + (tag >> 2));
                int pv = (int)((d >> ((tag & 3) << 3)) & 0xFFu);
                int m  = __shfl(mreg, q);
                tag = m ? pv : tag;
                if (l == 0) path[r] = tag;
            }
        }
    };

    loadChunk(7, dwA, mA);
    for (int c = 7; c >= 1; c -= 2) {
        loadChunk(c - 1, dwB, mB);
        procChunk(c, dwA, mA);
        if (c >= 2) loadChunk(c - 2, dwA, mA);
        procChunk(c - 1, dwB, mB);
    }

    __syncthreads();
#pragma unroll
    for (int cc = 0; cc < 8; ++cc)
        out[(size_t)b * TT + cc * 64 + l] = path[cc * 64 + l];
}

extern "C" void kernel_launch(void* const* d_in, const int* in_sizes, int n_in,
                              void* d_out, int out_size, void* d_ws, size_t ws_size,
                              hipStream_t stream) {
    const float* emissions = (const float*)d_in[0];
    const int* attn_mask   = (const int*)d_in[1];
    const float* start_t   = (const float*)d_in[2];
    const float* end_t     = (const float*)d_in[3];
    const float* trans     = (const float*)d_in[4];
    int* out = (int*)d_out;

    unsigned char* hist = (unsigned char*)d_ws;
    int* best_last = (int*)((char*)d_ws + (size_t)BB * TT * KK);

    viterbi_fwd<<<BB / 2, KK, 0, stream>>>(emissions, attn_mask, start_t, end_t,
                                           trans, hist, best_last);
    viterbi_bt<<<BB, KK, 0, stream>>>(hist, attn_mask, best_last, out);
}

// Round 8
// 480.288 us; speedup vs baseline: 1.7829x; 1.7829x over previous
//
#include <hip/hip_runtime.h>
#include <hip/hip_bf16.h>

// Viterbi CRF decode: B=512, T=512, K=64.
// Round 10: one wave per batch (512 waves), INSTRUCTION DIET.
// Evidence chain: r5-r8 (4 different inner loops) all ~400-412us; r9
// (2 batches interleaved per wave) scaled time by 1.87x -> the wave is
// ISSUE-RATE bound at ~4.4 cy/instr (single-wave cadence, no co-resident
// wave to fill issue slots; B=512 chains can't fill 1024 SIMDs deeper,
// and r0 showed cross-wave splitting pays ~1000cy/step in barriers).
// So: cut instructions. (a) score broadcast via LDS quads: 1 ds_write_b32
// (whole-wave, lockstep-visible, no barrier needed in a 1-wave block) +
// 16 uniform-address ds_read_b128 (uniform addr = broadcast, conflict-
// free) replaces 64 ds_bpermute: -47 instrs. (b) packed fp32: float2
// adds -> v_pk_add_f32 halves 128 adds to 64: -64 instrs. ~430 -> ~310
// instrs/step. Semantics untouched: FP association (s+tc)+e exact per
// half, 8 ascending strict-> chains of 8 merged low-group-first =>
// jnp.argmax first-index tie-break -> bitwise-identical output.
// Backtrace unchanged (verified).
// Workspace: hist uint8 [B][512][K] = 16.78 MB (row 511 pad) + best_last[B].

#define TT 512
#define BB 512
#define KK 64
#define RS 68   // padded row stride (floats) for transposed trans in LDS

typedef float v2f __attribute__((ext_vector_type(2)));

__global__ __launch_bounds__(64, 1) void viterbi_fwd(
    const float* __restrict__ emissions,   // [B,T,K]
    const int* __restrict__ attn_mask,     // [B,T]
    const float* __restrict__ start_t,     // [K]
    const float* __restrict__ end_t,       // [K]
    const float* __restrict__ trans,       // [K,K]
    unsigned char* __restrict__ hist,      // [B,512,K] (row 511 pad)
    int* __restrict__ best_last)           // [B]
{
    const int b = blockIdx.x;
    const int j = threadIdx.x & 63;

    // transposed + padded transitions: ldsT[j*RS + i] = trans[i][j]
    __shared__ __align__(16) float ldsT[KK * RS];   // 17408 B
    __shared__ __align__(16) float ldsS[KK];        // score publish buffer
    __shared__ float sv[KK];

#pragma unroll 4
    for (int i = 0; i < KK; ++i)
        ldsT[j * RS + i] = trans[i * KK + j];
    __syncthreads();

    const float* row = &ldsT[j * RS];

    const float* eb = emissions + (size_t)b * TT * KK;
    const int*   mb = attn_mask + (size_t)b * TT;
    unsigned char* hb = hist + (size_t)b * TT * KK;

    // score vector lives lane-distributed: lane j holds score[j]
    float score = start_t[j] + eb[j];

    // 2-deep prefetch rings for emissions row and mask
    float e0 = eb[KK + j];
    float e1 = eb[2 * KK + j];
    int   m0 = mb[1];
    int   m1 = mb[2];

    for (int t = 1; t < TT; ++t) {
        float e = e0; e0 = e1;
        int   m = m0; m0 = m1;
        int tn = (t + 2 < TT) ? (t + 2) : (TT - 1);
        e1 = eb[(size_t)tn * KK + j];
        m1 = mb[tn];

        // publish this step's score vector (whole-wave ds_write_b32;
        // lanes are in lockstep within the single wave -> subsequent
        // reads see all 64 values, no barrier needed)
        ldsS[j] = score;

        // opaque zero offset: loop-variant address -> no LICM of the
        // loop-invariant tc reads (r3-r6 spill/remat pathology), while
        // keeping addrspace(3) provenance -> ds_read_b128 + imm offsets.
        unsigned off = 0;
        asm volatile("" : "+v"(off));
        const float* rb = row + off;
        const float* sb = &ldsS[0];     // uniform address -> broadcast reads

        v2f e2; e2[0] = e; e2[1] = e;

        float gv[8];
        int   gi[8];

#pragma unroll
        for (int g = 0; g < 8; ++g) {
            float4 S0 = *(const float4*)(sb + 8 * g);
            float4 S1 = *(const float4*)(sb + 8 * g + 4);
            float4 T0 = *(const float4*)(rb + 8 * g);
            float4 T1 = *(const float4*)(rb + 8 * g + 4);

            // packed (s + t) + e, exact association per half
            v2f c01 = ((v2f){S0.x, S0.y} + (v2f){T0.x, T0.y}) + e2;
            v2f c23 = ((v2f){S0.z, S0.w} + (v2f){T0.z, T0.w}) + e2;
            v2f c45 = ((v2f){S1.x, S1.y} + (v2f){T1.x, T1.y}) + e2;
            v2f c67 = ((v2f){S1.z, S1.w} + (v2f){T1.z, T1.w}) + e2;

            const int base = 8 * g;
            // ascending strict-> chain (first-index tie rule)
            float bv = c01[0]; int bi = base;
            float c;
            c = c01[1]; if (c > bv) { bv = c; bi = base + 1; }
            c = c23[0]; if (c > bv) { bv = c; bi = base + 2; }
            c = c23[1]; if (c > bv) { bv = c; bi = base + 3; }
            c = c45[0]; if (c > bv) { bv = c; bi = base + 4; }
            c = c45[1]; if (c > bv) { bv = c; bi = base + 5; }
            c = c67[0]; if (c > bv) { bv = c; bi = base + 6; }
            c = c67[1]; if (c > bv) { bv = c; bi = base + 7; }
            gv[g] = bv;
            gi[g] = bi;
        }

        // merge group winners ascending (first-index tie rule preserved)
        float best = gv[0];
        int   bi   = gi[0];
#pragma unroll
        for (int g = 1; g < 8; ++g)
            if (gv[g] > best) { best = gv[g]; bi = gi[g]; }

        // history recorded unconditionally (mask applied in backtrace)
        hb[(size_t)(t - 1) * KK + j] = (unsigned char)bi;
        // freeze past sequence end
        score = m ? best : score;
    }

    // final: add end transitions, argmax over tags (first-index ties)
    float fin = score + end_t[j];
    sv[j] = fin;
    __syncthreads();
    if (j == 0) {
        float bv = sv[0];
        int   bt = 0;
#pragma unroll
        for (int k = 1; k < KK; ++k) {
            float v = sv[k];
            if (v > bv) { bv = v; bt = k; }
        }
        best_last[b] = bt;
    }
}

__global__ __launch_bounds__(64) void viterbi_bt(
    const unsigned char* __restrict__ hist,  // [B,512,K]
    const int* __restrict__ attn_mask,       // [B,T]
    const int* __restrict__ best_last,       // [B]
    int* __restrict__ out)                   // [B,T] int32
{
    const int b = blockIdx.x;
    const int l = threadIdx.x;
    __shared__ int path[TT];

    const unsigned int* hw = (const unsigned int*)(hist + (size_t)b * TT * KK);
    const int* mb = attn_mask + (size_t)b * TT;

    int tag = best_last[b];          // broadcast (uniform on all lanes)
    if (l == 0) path[TT - 1] = tag;

    unsigned int dwA[16], dwB[16];
    int mA, mB;

    auto loadChunk = [&](int c, unsigned int (&dw)[16], int& mreg) {
#pragma unroll
        for (int q4 = 0; q4 < 16; ++q4)
            dw[q4] = hw[c * 1024 + q4 * 64 + l];   // 4 rows per wave-load
        int midx = c * 64 + l + 1;
        if (midx > TT - 1) midx = TT - 1;
        mreg = mb[midx];                            // lane l: mask[b][c*64+l+1]
    };
    auto procChunk = [&](int c, unsigned int (&dw)[16], int mreg) {
#pragma unroll
        for (int q = 63; q >= 0; --q) {
            int r = c * 64 + q;
            if (r < TT - 1) {
                // byte hist[r][tag]: local dword q*16+(tag>>2)
                unsigned int d = __shfl(dw[q >> 2], ((q & 3) << 4) + (tag >> 2));
                int pv = (int)((d >> ((tag & 3) << 3)) & 0xFFu);
                int m  = __shfl(mreg, q);
                tag = m ? pv : tag;
                if (l == 0) path[r] = tag;
            }
        }
    };

    loadChunk(7, dwA, mA);
    for (int c = 7; c >= 1; c -= 2) {
        loadChunk(c - 1, dwB, mB);
        procChunk(c, dwA, mA);
        if (c >= 2) loadChunk(c - 2, dwA, mA);
        procChunk(c - 1, dwB, mB);
    }

    __syncthreads();
#pragma unroll
    for (int cc = 0; cc < 8; ++cc)
        out[(size_t)b * TT + cc * 64 + l] = path[cc * 64 + l];
}

extern "C" void kernel_launch(void* const* d_in, const int* in_sizes, int n_in,
                              void* d_out, int out_size, void* d_ws, size_t ws_size,
                              hipStream_t stream) {
    const float* emissions = (const float*)d_in[0];
    const int* attn_mask   = (const int*)d_in[1];
    const float* start_t   = (const float*)d_in[2];
    const float* end_t     = (const float*)d_in[3];
    const float* trans     = (const float*)d_in[4];
    int* out = (int*)d_out;

    unsigned char* hist = (unsigned char*)d_ws;
    int* best_last = (int*)((char*)d_ws + (size_t)BB * TT * KK);

    viterbi_fwd<<<BB, KK, 0, stream>>>(emissions, attn_mask, start_t, end_t,
                                       trans, hist, best_last);
    viterbi_bt<<<BB, KK, 0, stream>>>(hist, attn_mask, best_last, out);
}